// Round 1
// baseline (332.504 us; speedup 1.0000x reference)
//
#include <hip/hip_runtime.h>

#define S 128
#define SS (S * S)

// One thread per output pixel (b, i, j). Marches up to 128 trilinear taps
// along the rotated ray, accumulates, writes one float.
//
// Reference math:
//   coords(i,j,k)    = (lin[j], lin[i], lin[k]),  lin[t] = -1 + 2t/127
//   p(b,i,j,k)       = lin[j]*R[b,0,:] + lin[i]*R[b,1,:] + lin[k]*R[b,2,:]
//   unnormalized     u = (p + 1) * 63.5          (align_corners=True)
//   vol index        (z*128 + y)*128 + x          (vol is [D,H,W], p=(x,y,z))
//   out[b,0,i,j]     = sum_k trilinear(vol, u(k))  (zero padding)
//
// Since (2/127)*63.5 == 1.0 exactly, the per-k step in voxel space is exactly
// the rotation row R[b,2,:].
__global__ __launch_bounds__(256) void projector_kernel(
    const float* __restrict__ rot,   // [16,3,3]
    const float* __restrict__ vol,   // [128,128,128]
    float* __restrict__ out)         // [16,1,128,128]
{
    const int pix = blockIdx.x * 256 + threadIdx.x;
    const int b   = pix >> 14;       // 16384 pixels per batch item
    const int rem = pix & 16383;
    const int i   = rem >> 7;
    const int j   = rem & 127;

    // All threads of a block share b (64 blocks per batch item) -> scalar loads
    const float* Rb = rot + b * 9;
    const float r00 = Rb[0], r01 = Rb[1], r02 = Rb[2];
    const float r10 = Rb[3], r11 = Rb[4], r12 = Rb[5];
    const float r20 = Rb[6], r21 = Rb[7], r22 = Rb[8];

    const float step = 2.0f / 127.0f;
    const float li = -1.0f + step * (float)i;
    const float lj = -1.0f + step * (float)j;

    // Voxel-space position at k=0 (lk = -1) and per-k step (== R row 2).
    const float ix0 = (lj * r00 + li * r10 - r20 + 1.0f) * 63.5f;
    const float iy0 = (lj * r01 + li * r11 - r21 + 1.0f) * 63.5f;
    const float iz0 = (lj * r02 + li * r12 - r22 + 1.0f) * 63.5f;
    const float ux = r20, uy = r21, uz = r22;

    // Analytic ray/cube clip: contribution possible only while each coord is
    // in (-1, 128). Widen by 1 step for float safety; per-corner validity
    // checks below make extra iterations contribute exactly 0.
    float klo = 0.0f, khi = 127.0f;
    {
        const float lo = -1.0f, hi = 128.0f;
        // x
        if (fabsf(ux) > 1e-7f) {
            float a = (lo - ix0) / ux, c = (hi - ix0) / ux;
            klo = fmaxf(klo, fminf(a, c)); khi = fminf(khi, fmaxf(a, c));
        } else if (ix0 <= lo || ix0 >= hi) { klo = 1e9f; khi = -1e9f; }
        // y
        if (fabsf(uy) > 1e-7f) {
            float a = (lo - iy0) / uy, c = (hi - iy0) / uy;
            klo = fmaxf(klo, fminf(a, c)); khi = fminf(khi, fmaxf(a, c));
        } else if (iy0 <= lo || iy0 >= hi) { klo = 1e9f; khi = -1e9f; }
        // z
        if (fabsf(uz) > 1e-7f) {
            float a = (lo - iz0) / uz, c = (hi - iz0) / uz;
            klo = fmaxf(klo, fminf(a, c)); khi = fminf(khi, fmaxf(a, c));
        } else if (iz0 <= lo || iz0 >= hi) { klo = 1e9f; khi = -1e9f; }
    }
    int kmin = 0, kmax = -1;
    if (klo <= khi) {
        kmin = max(0,   (int)floorf(klo) - 1);
        kmax = min(127, (int)ceilf(khi) + 1);
    }

    float acc = 0.0f;
    for (int k = kmin; k <= kmax; ++k) {
        const float kk = (float)k;
        const float ix = fmaf(kk, ux, ix0);
        const float iy = fmaf(kk, uy, iy0);
        const float iz = fmaf(kk, uz, iz0);

        const float xf = floorf(ix), yf = floorf(iy), zf = floorf(iz);
        const float fx = ix - xf, fy = iy - yf, fz = iz - zf;
        const int x0 = (int)xf, y0 = (int)yf, z0 = (int)zf;

        float v000, v001, v010, v011, v100, v101, v110, v111;
        if (((unsigned)x0 < 127u) & ((unsigned)y0 < 127u) & ((unsigned)z0 < 127u)) {
            // Interior: whole 2x2x2 cell in-bounds.
            const float* p = vol + ((z0 * S + y0) * S + x0);
            v000 = p[0];        v001 = p[1];
            v010 = p[S];        v011 = p[S + 1];
            v100 = p[SS];       v101 = p[SS + 1];
            v110 = p[SS + S];   v111 = p[SS + S + 1];
        } else {
            const int x1 = x0 + 1, y1 = y0 + 1, z1 = z0 + 1;
            const bool vx0 = (unsigned)x0 < 128u, vx1 = (unsigned)x1 < 128u;
            const bool vy0 = (unsigned)y0 < 128u, vy1 = (unsigned)y1 < 128u;
            const bool vz0 = (unsigned)z0 < 128u, vz1 = (unsigned)z1 < 128u;
            v000 = (vx0 && vy0 && vz0) ? vol[(z0 * S + y0) * S + x0] : 0.0f;
            v001 = (vx1 && vy0 && vz0) ? vol[(z0 * S + y0) * S + x1] : 0.0f;
            v010 = (vx0 && vy1 && vz0) ? vol[(z0 * S + y1) * S + x0] : 0.0f;
            v011 = (vx1 && vy1 && vz0) ? vol[(z0 * S + y1) * S + x1] : 0.0f;
            v100 = (vx0 && vy0 && vz1) ? vol[(z1 * S + y0) * S + x0] : 0.0f;
            v101 = (vx1 && vy0 && vz1) ? vol[(z1 * S + y0) * S + x1] : 0.0f;
            v110 = (vx0 && vy1 && vz1) ? vol[(z1 * S + y1) * S + x0] : 0.0f;
            v111 = (vx1 && vy1 && vz1) ? vol[(z1 * S + y1) * S + x1] : 0.0f;
        }

        const float c00 = v000 + fx * (v001 - v000);
        const float c01 = v010 + fx * (v011 - v010);
        const float c10 = v100 + fx * (v101 - v100);
        const float c11 = v110 + fx * (v111 - v110);
        const float c0  = c00 + fy * (c01 - c00);
        const float c1  = c10 + fy * (c11 - c10);
        acc += c0 + fz * (c1 - c0);
    }

    out[pix] = acc;   // out flat index == pix: b*16384 + i*128 + j
}

extern "C" void kernel_launch(void* const* d_in, const int* in_sizes, int n_in,
                              void* d_out, int out_size, void* d_ws, size_t ws_size,
                              hipStream_t stream) {
    const float* rot = (const float*)d_in[0];   // [16,3,3]
    const float* vol = (const float*)d_in[1];   // [128^3]
    // d_in[2] = proj_axis (always 3) — baked into the kernel.
    float* out = (float*)d_out;                 // [16*128*128]

    const int total = 16 * S * S;               // 262144
    projector_kernel<<<total / 256, 256, 0, stream>>>(rot, vol, out);
}

// Round 2
// 209.465 us; speedup vs baseline: 1.5874x; 1.5874x over previous
//
#include <hip/hip_runtime.h>
#include <hip/hip_fp16.h>

#define S 128
#define SS (S * S)

// ---------------------------------------------------------------------------
// Prep: fp32 volume -> fp16 volume in workspace (4 MB, fits per-XCD L2).
// Runs every call (idempotent, deterministic).
// ---------------------------------------------------------------------------
__global__ __launch_bounds__(256) void convert_kernel(
    const float* __restrict__ vol, __half* __restrict__ vol16)
{
    const int t = blockIdx.x * 256 + threadIdx.x;        // 4 elems per thread
    const float4 f = ((const float4*)vol)[t];
    __half2* o = (__half2*)(vol16 + t * 4);
    o[0] = __floats2half2_rn(f.x, f.y);
    o[1] = __floats2half2_rn(f.z, f.w);
}

__device__ __forceinline__ float ldv(const float* p)  { return *p; }
__device__ __forceinline__ float ldv(const __half* p) { return __half2float(*p); }

// ---------------------------------------------------------------------------
// One thread per (output pixel, k-segment). 8x8 pixel tile per wave,
// 16x16 tile per block. Marches trilinear taps along the rotated ray for
// its k-segment, atomically accumulates into out (2 partials per pixel).
// ---------------------------------------------------------------------------
template <typename T>
__global__ __launch_bounds__(256) void projector_kernel(
    const float* __restrict__ rot,   // [16,3,3]
    const T* __restrict__ vol,       // [128,128,128]
    float* __restrict__ out)         // [16,1,128,128], pre-zeroed
{
    // Grid: 2048 = seg(2) x b(16) x tile(64)
    const int blk  = blockIdx.x;
    const int seg  = blk >> 10;
    const int rest = blk & 1023;
    const int b    = rest >> 6;
    const int tile = rest & 63;          // 8x8 tiles of 16x16 pixels
    const int tY   = tile >> 3, tX = tile & 7;

    const int wave = threadIdx.x >> 6;   // 2x2 waves inside block
    const int lane = threadIdx.x & 63;   // 8x8 pixels inside wave
    const int i = tY * 16 + (wave >> 1) * 8 + (lane >> 3);
    const int j = tX * 16 + (wave & 1) * 8 + (lane & 7);

    const float* Rb = rot + b * 9;
    const float r00 = Rb[0], r01 = Rb[1], r02 = Rb[2];
    const float r10 = Rb[3], r11 = Rb[4], r12 = Rb[5];
    const float r20 = Rb[6], r21 = Rb[7], r22 = Rb[8];

    const float step = 2.0f / 127.0f;
    const float li = -1.0f + step * (float)i;
    const float lj = -1.0f + step * (float)j;

    // Voxel-space position at k=0 and per-k step (== rotation row 2, unit).
    const float ix0 = (lj * r00 + li * r10 - r20 + 1.0f) * 63.5f;
    const float iy0 = (lj * r01 + li * r11 - r21 + 1.0f) * 63.5f;
    const float iz0 = (lj * r02 + li * r12 - r22 + 1.0f) * 63.5f;
    const float ux = r20, uy = r21, uz = r22;

    // Analytic ray/cube clip to (-1, 128) per coord; widened by 1 step.
    float klo = 0.0f, khi = 127.0f;
    {
        const float lo = -1.0f, hi = 128.0f;
        if (fabsf(ux) > 1e-7f) {
            float a = (lo - ix0) / ux, c = (hi - ix0) / ux;
            klo = fmaxf(klo, fminf(a, c)); khi = fminf(khi, fmaxf(a, c));
        } else if (ix0 <= lo || ix0 >= hi) { klo = 1e9f; khi = -1e9f; }
        if (fabsf(uy) > 1e-7f) {
            float a = (lo - iy0) / uy, c = (hi - iy0) / uy;
            klo = fmaxf(klo, fminf(a, c)); khi = fminf(khi, fmaxf(a, c));
        } else if (iy0 <= lo || iy0 >= hi) { klo = 1e9f; khi = -1e9f; }
        if (fabsf(uz) > 1e-7f) {
            float a = (lo - iz0) / uz, c = (hi - iz0) / uz;
            klo = fmaxf(klo, fminf(a, c)); khi = fminf(khi, fmaxf(a, c));
        } else if (iz0 <= lo || iz0 >= hi) { klo = 1e9f; khi = -1e9f; }
    }
    int kmin = seg * 64, kmax = seg * 64 + 63;
    if (klo <= khi) {
        kmin = max(kmin, (int)floorf(klo) - 1);
        kmax = min(kmax, (int)ceilf(khi) + 1);
    } else {
        kmax = kmin - 1;   // no intersection
    }

    float acc = 0.0f;
    for (int k = kmin; k <= kmax; ++k) {
        const float kk = (float)k;
        const float ix = fmaf(kk, ux, ix0);
        const float iy = fmaf(kk, uy, iy0);
        const float iz = fmaf(kk, uz, iz0);

        const float xf = floorf(ix), yf = floorf(iy), zf = floorf(iz);
        const float fx = ix - xf, fy = iy - yf, fz = iz - zf;
        const int x0 = (int)xf, y0 = (int)yf, z0 = (int)zf;

        float v000, v001, v010, v011, v100, v101, v110, v111;
        if (((unsigned)x0 < 127u) & ((unsigned)y0 < 127u) & ((unsigned)z0 < 127u)) {
            const T* p = vol + ((z0 * S + y0) * S + x0);
            v000 = ldv(p);          v001 = ldv(p + 1);
            v010 = ldv(p + S);      v011 = ldv(p + S + 1);
            v100 = ldv(p + SS);     v101 = ldv(p + SS + 1);
            v110 = ldv(p + SS + S); v111 = ldv(p + SS + S + 1);
        } else {
            const int x1 = x0 + 1, y1 = y0 + 1, z1 = z0 + 1;
            const bool vx0 = (unsigned)x0 < 128u, vx1 = (unsigned)x1 < 128u;
            const bool vy0 = (unsigned)y0 < 128u, vy1 = (unsigned)y1 < 128u;
            const bool vz0 = (unsigned)z0 < 128u, vz1 = (unsigned)z1 < 128u;
            v000 = (vx0 && vy0 && vz0) ? ldv(vol + (z0 * S + y0) * S + x0) : 0.0f;
            v001 = (vx1 && vy0 && vz0) ? ldv(vol + (z0 * S + y0) * S + x1) : 0.0f;
            v010 = (vx0 && vy1 && vz0) ? ldv(vol + (z0 * S + y1) * S + x0) : 0.0f;
            v011 = (vx1 && vy1 && vz0) ? ldv(vol + (z0 * S + y1) * S + x1) : 0.0f;
            v100 = (vx0 && vy0 && vz1) ? ldv(vol + (z1 * S + y0) * S + x0) : 0.0f;
            v101 = (vx1 && vy0 && vz1) ? ldv(vol + (z1 * S + y0) * S + x1) : 0.0f;
            v110 = (vx0 && vy1 && vz1) ? ldv(vol + (z1 * S + y1) * S + x0) : 0.0f;
            v111 = (vx1 && vy1 && vz1) ? ldv(vol + (z1 * S + y1) * S + x1) : 0.0f;
        }

        const float c00 = v000 + fx * (v001 - v000);
        const float c01 = v010 + fx * (v011 - v010);
        const float c10 = v100 + fx * (v101 - v100);
        const float c11 = v110 + fx * (v111 - v110);
        const float c0  = c00 + fy * (c01 - c00);
        const float c1  = c10 + fy * (c11 - c10);
        acc += c0 + fz * (c1 - c0);
    }

    // 2 commutative fp32 adds per address -> deterministic.
    atomicAdd(&out[(b << 14) + (i << 7) + j], acc);
}

extern "C" void kernel_launch(void* const* d_in, const int* in_sizes, int n_in,
                              void* d_out, int out_size, void* d_ws, size_t ws_size,
                              hipStream_t stream) {
    const float* rot = (const float*)d_in[0];   // [16,3,3]
    const float* vol = (const float*)d_in[1];   // [128^3] fp32
    float* out = (float*)d_out;                 // [16*128*128]

    hipMemsetAsync(out, 0, (size_t)out_size * sizeof(float), stream);

    const size_t need = (size_t)SS * S * sizeof(__half);   // 4 MB
    if (ws_size >= need) {
        __half* vol16 = (__half*)d_ws;
        convert_kernel<<<(SS * S / 4) / 256, 256, 0, stream>>>(vol, vol16);
        projector_kernel<__half><<<2048, 256, 0, stream>>>(rot, vol16, out);
    } else {
        projector_kernel<float><<<2048, 256, 0, stream>>>(rot, vol, out);
    }
}